// Round 2
// baseline (413.614 us; speedup 1.0000x reference)
//
#include <hip/hip_runtime.h>
#include <hip/hip_bf16.h>
#include <stdint.h>

// out[2048,256] = x[2048,32768] @ W[32768,256],
// W[k,r] = U0[k&31, r] * U1[(k>>5)&31, r] * U2[k>>10, r]
//
// R2: (1) wgen with coalesced loads (lanes sweep r), swizzled bf16 W^T tiles
//     (2) GEMM 128x256 tile (full R per block -> x read once), split-K=32,
//         partials to d_ws via plain stores (NO atomics)
//     (3) reduce kernel sums 32 partials -> d_out.

#define K_DIM 32768
#define R_DIM 256
#define M_DIM 2048
#define BM 128
#define BN 256
#define BK 64
#define SK 32
#define KC (K_DIM / SK)   // 1024 K per block
#define NKI (KC / BK)     // 16 iterations
#define OUT_ELEMS (M_DIM * R_DIM)   // 524288

typedef float f32x4 __attribute__((ext_vector_type(4)));
typedef short s16x8 __attribute__((ext_vector_type(8)));

// pack two fp32 -> two bf16 (round via +0x8000, v_perm byte pick)
__device__ __forceinline__ uint32_t pack2_bf16(float a, float b) {
    uint32_t ua = __builtin_bit_cast(uint32_t, a) + 0x8000u;
    uint32_t ub = __builtin_bit_cast(uint32_t, b) + 0x8000u;
    return __builtin_amdgcn_perm(ub, ua, 0x07060302u);
}

__device__ __forceinline__ void async_load16(const void* g, void* lds) {
    __builtin_amdgcn_global_load_lds(
        (const __attribute__((address_space(1))) void*)g,
        (__attribute__((address_space(3))) void*)lds, 16, 0, 0);
}

// ---------------------------------------------------------------------------
// Kernel 1: W^T bf16, layout = 512 k-tiles of 64 k x 256 r:
//   Wsw[t*16384 + r*64 + pos*8 .. +8) = W[k = t*64 + c*8 .. +8][r],
//   pos = c ^ (r & 7)   (XOR swizzle, identical to the GEMM's LDS layout,
//   so staging is an async identity copy).
// Thread (t, r): lanes sweep r -> every U load is coalesced.
// ---------------------------------------------------------------------------
__global__ __launch_bounds__(256) void wgen_kernel(
        const float* __restrict__ U0, const float* __restrict__ U1,
        const float* __restrict__ U2, uint16_t* __restrict__ Wsw) {
    uint32_t tid = blockIdx.x * 256u + threadIdx.x;   // [0, 131072)
    uint32_t r   = tid & 255u;
    uint32_t t   = tid >> 8;                          // [0, 512)
    uint32_t kb  = t * 64u;
    float u2 = U2[(kb >> 10) * 256u + r];
    uint16_t* rowp = Wsw + (size_t)t * 16384u + r * 64u;
    uint32_t rs = (r & 7u) * 8u;
#pragma unroll
    for (uint32_t c = 0; c < 8; ++c) {
        uint32_t k0  = kb + c * 8u;
        uint32_t i1  = (k0 >> 5) & 31u;
        uint32_t i0b = k0 & 31u;          // +e stays in [0,32): 8-aligned
        float u12 = U1[i1 * 256u + r] * u2;
        float w[8];
#pragma unroll
        for (int e = 0; e < 8; ++e)
            w[e] = U0[(i0b + (uint32_t)e) * 256u + r] * u12;
        uint32_t q0 = pack2_bf16(w[0], w[1]);
        uint32_t q1 = pack2_bf16(w[2], w[3]);
        uint32_t q2 = pack2_bf16(w[4], w[5]);
        uint32_t q3 = pack2_bf16(w[6], w[7]);
        *(uint4*)(rowp + ((c * 8u) ^ rs)) = make_uint4(q0, q1, q2, q3);
    }
}

// ---------------------------------------------------------------------------
// Kernel 2: GEMM. 256 threads = 4 waves, 2x2 over the 128x256 tile
// (64x128 per wave, 4x8 grid of 16x16x32 bf16 MFMA). Grid: 16 mblk x 32 sk.
// Partials -> part[sk][2048][256] in d_ws (plain stores, no atomics).
// ---------------------------------------------------------------------------
__global__ __launch_bounds__(256, 2) void gemm_kernel(
        const float* __restrict__ x, const uint16_t* __restrict__ Wsw,
        float* __restrict__ part) {
    __shared__ uint16_t As[BM * 64];   // 16 KB
    __shared__ uint16_t Bs[BN * 64];   // 32 KB

    const uint32_t bid  = blockIdx.x;
    const uint32_t sk   = bid & 31u;
    const uint32_t mblk = bid >> 5;

    const uint32_t tid  = threadIdx.x;
    const uint32_t lane = tid & 63u;
    const uint32_t wave = tid >> 6;

    // ---- A staging: fp32 -> bf16 in-register, swizzled ds_write_b128 ----
    const uint32_t ac   = tid & 7u;     // k-chunk (8 floats)
    const uint32_t arow = tid >> 3;     // rows arow + {0,32,64,96}
    const uint32_t aswz = (ac ^ (arow & 7u)) * 8u;
    const float* xg = x + (size_t)(mblk * BM + arow) * K_DIM + sk * KC + ac * 8u;

    // ---- B staging: async identity copy of pre-swizzled tiles ----
    const uint16_t* wg_base = Wsw + (size_t)(sk * NKI) * 16384u;

    // ---- fragment addressing ----
    const uint32_t mloc = lane & 15u;
    const uint32_t quad = lane >> 4;
    const uint32_t wm = wave >> 1, wn = wave & 1u;
    const uint32_t sw0 = ((quad) ^ (mloc & 7u)) * 8u;        // ks=0
    const uint32_t sw1 = ((4u + quad) ^ (mloc & 7u)) * 8u;   // ks=1
    const uint32_t aRow0 = (wm * 64u + mloc) * 64u;
    const uint32_t bRow0 = (wn * 128u + mloc) * 64u;

    f32x4 acc[4][8];
#pragma unroll
    for (int i = 0; i < 4; ++i)
#pragma unroll
        for (int j = 0; j < 8; ++j) acc[i][j] = (f32x4){0.f, 0.f, 0.f, 0.f};

    for (uint32_t it = 0; it < NKI; ++it) {
        // B: 2048 chunks of 16B; 8 async_load16 per thread, identity copy
        const uint16_t* wg_tile = wg_base + (size_t)it * 16384u;
#pragma unroll
        for (int j = 0; j < 8; ++j) {
            uint32_t base_chunk = (uint32_t)j * 256u + wave * 64u;  // wave-uniform
            const uint16_t* g = wg_tile + (size_t)(base_chunk + lane) * 8u;
            async_load16((const void*)g, (void*)&Bs[base_chunk * 8u]);
        }
        // A: 4 rows x 8 floats per thread, convert + swizzled write
#pragma unroll
        for (int j = 0; j < 4; ++j) {
            const float* g = xg + (size_t)(j * 32) * K_DIM + it * BK;
            f32x4 v0 = *(const f32x4*)(g);
            f32x4 v1 = *(const f32x4*)(g + 4);
            uint32_t q0 = pack2_bf16(v0[0], v0[1]);
            uint32_t q1 = pack2_bf16(v0[2], v0[3]);
            uint32_t q2 = pack2_bf16(v1[0], v1[1]);
            uint32_t q3 = pack2_bf16(v1[2], v1[3]);
            *(uint4*)(&As[(arow + (uint32_t)j * 32u) * 64u + aswz]) =
                make_uint4(q0, q1, q2, q3);
        }
        __syncthreads();

#pragma unroll
        for (int ks = 0; ks < 2; ++ks) {
            const uint32_t sw = ks ? sw1 : sw0;
            s16x8 af[4], bf[8];
#pragma unroll
            for (int t = 0; t < 4; ++t)
                af[t] = *(const s16x8*)(&As[aRow0 + (uint32_t)t * 1024u + sw]);
#pragma unroll
            for (int t = 0; t < 8; ++t)
                bf[t] = *(const s16x8*)(&Bs[bRow0 + (uint32_t)t * 1024u + sw]);
#pragma unroll
            for (int mt = 0; mt < 4; ++mt)
#pragma unroll
                for (int nt = 0; nt < 8; ++nt)
                    acc[mt][nt] = __builtin_amdgcn_mfma_f32_16x16x32_bf16(
                        af[mt], bf[nt], acc[mt][nt], 0, 0, 0);
        }
        __syncthreads();
    }

    // epilogue: plain stores of the split-K partial
    float* po_base = part + (size_t)sk * OUT_ELEMS;
    const uint32_t orow0 = mblk * BM + wm * 64u + quad * 4u;
    const uint32_t ocol0 = wn * 128u + mloc;
#pragma unroll
    for (int mt = 0; mt < 4; ++mt) {
#pragma unroll
        for (int nt = 0; nt < 8; ++nt) {
            float* po = po_base + (size_t)(orow0 + (uint32_t)mt * 16u) * R_DIM +
                        ocol0 + (uint32_t)nt * 16u;
#pragma unroll
            for (int i = 0; i < 4; ++i)
                po[(size_t)i * R_DIM] = acc[mt][nt][i];
        }
    }
}

// ---------------------------------------------------------------------------
// Kernel 3: out[i] = sum_sk part[sk][i], float4 per thread.
// ---------------------------------------------------------------------------
__global__ __launch_bounds__(256) void reduce_kernel(
        const float* __restrict__ part, float* __restrict__ out) {
    uint32_t i = (blockIdx.x * 256u + threadIdx.x) * 4u;
    f32x4 s = (f32x4){0.f, 0.f, 0.f, 0.f};
#pragma unroll
    for (uint32_t skk = 0; skk < SK; ++skk)
        s += *(const f32x4*)(part + (size_t)skk * OUT_ELEMS + i);
    *(f32x4*)(out + i) = s;
}

extern "C" void kernel_launch(void* const* d_in, const int* in_sizes, int n_in,
                              void* d_out, int out_size, void* d_ws, size_t ws_size,
                              hipStream_t stream) {
    const float* x  = (const float*)d_in[0];
    const float* U0 = (const float*)d_in[1];
    const float* U1 = (const float*)d_in[2];
    const float* U2 = (const float*)d_in[3];
    float* out = (float*)d_out;

    uint16_t* Wsw = (uint16_t*)d_ws;                          // 16 MiB
    float* part = (float*)((char*)d_ws + (32u << 20));        // 64 MiB partials

    wgen_kernel<<<512, 256, 0, stream>>>(U0, U1, U2, Wsw);
    gemm_kernel<<<512, 256, 0, stream>>>(x, Wsw, part);
    reduce_kernel<<<OUT_ELEMS / 4 / 256, 256, 0, stream>>>(part, out);
}

// Round 3
// 408.500 us; speedup vs baseline: 1.0125x; 1.0125x over previous
//
#include <hip/hip_runtime.h>
#include <hip/hip_bf16.h>
#include <stdint.h>

// out[2048,256] = x[2048,32768] @ W[32768,256],
// W[k,r] = U0[k&31, r] * U1[(k>>5)&31, r] * U2[k>>10, r]
//
// R3: gemm restructured to 512-thread blocks (8 waves, 2x4 over the 128x256
// tile) -> acc = 64 VGPR/thread, __launch_bounds__(512,4) targets 16 waves/CU
// (2 blocks/CU), double R2's occupancy. B staged via async identity copy of
// pre-swizzled bf16 tiles; A converted fp32->bf16 in-register; split-K=32
// partials -> plain stores -> reduce kernel.

#define K_DIM 32768
#define R_DIM 256
#define M_DIM 2048
#define BM 128
#define BN 256
#define BK 64
#define SK 32
#define KC (K_DIM / SK)   // 1024 K per block
#define NKI (KC / BK)     // 16 iterations
#define OUT_ELEMS (M_DIM * R_DIM)   // 524288

typedef float f32x4 __attribute__((ext_vector_type(4)));
typedef short s16x8 __attribute__((ext_vector_type(8)));

// pack two fp32 -> two bf16 (round via +0x8000, v_perm byte pick)
__device__ __forceinline__ uint32_t pack2_bf16(float a, float b) {
    uint32_t ua = __builtin_bit_cast(uint32_t, a) + 0x8000u;
    uint32_t ub = __builtin_bit_cast(uint32_t, b) + 0x8000u;
    return __builtin_amdgcn_perm(ub, ua, 0x07060302u);
}

__device__ __forceinline__ void async_load16(const void* g, void* lds) {
    __builtin_amdgcn_global_load_lds(
        (const __attribute__((address_space(1))) void*)g,
        (__attribute__((address_space(3))) void*)lds, 16, 0, 0);
}

// ---------------------------------------------------------------------------
// Kernel 1: W^T bf16, 512 k-tiles of 64 k x 256 r:
//   Wsw[t*16384 + r*64 + pos*8 .. +8) = W[k = t*64 + c*8 .. +8][r],
//   pos = c ^ (r & 7)  (same XOR swizzle as the GEMM's LDS layout ->
//   staging is an async identity copy). Lanes sweep r: coalesced U loads.
// ---------------------------------------------------------------------------
__global__ __launch_bounds__(256) void wgen_kernel(
        const float* __restrict__ U0, const float* __restrict__ U1,
        const float* __restrict__ U2, uint16_t* __restrict__ Wsw) {
    uint32_t tid = blockIdx.x * 256u + threadIdx.x;   // [0, 131072)
    uint32_t r   = tid & 255u;
    uint32_t t   = tid >> 8;                          // [0, 512)
    uint32_t kb  = t * 64u;
    float u2 = U2[(kb >> 10) * 256u + r];
    uint16_t* rowp = Wsw + (size_t)t * 16384u + r * 64u;
    uint32_t rs = (r & 7u) * 8u;
#pragma unroll
    for (uint32_t c = 0; c < 8; ++c) {
        uint32_t k0  = kb + c * 8u;
        uint32_t i1  = (k0 >> 5) & 31u;
        uint32_t i0b = k0 & 31u;
        float u12 = U1[i1 * 256u + r] * u2;
        float w[8];
#pragma unroll
        for (int e = 0; e < 8; ++e)
            w[e] = U0[(i0b + (uint32_t)e) * 256u + r] * u12;
        uint32_t q0 = pack2_bf16(w[0], w[1]);
        uint32_t q1 = pack2_bf16(w[2], w[3]);
        uint32_t q2 = pack2_bf16(w[4], w[5]);
        uint32_t q3 = pack2_bf16(w[6], w[7]);
        *(uint4*)(rowp + ((c * 8u) ^ rs)) = make_uint4(q0, q1, q2, q3);
    }
}

// ---------------------------------------------------------------------------
// Kernel 2: GEMM. 512 threads = 8 waves, 2(m) x 4(n) over 128x256 tile;
// wave tile 64x64 = 4x4 grid of 16x16x32 bf16 MFMA -> acc 64 VGPR/thread.
// Grid: 16 mblk x 32 sk = 512 blocks (same-sk blocks land on one XCD under
// round-robin dispatch -> B slice L2-resident). Partials via plain stores.
// ---------------------------------------------------------------------------
__global__ __launch_bounds__(512, 4) void gemm_kernel(
        const float* __restrict__ x, const uint16_t* __restrict__ Wsw,
        float* __restrict__ part) {
    __shared__ uint16_t As[BM * 64];   // 16 KB
    __shared__ uint16_t Bs[BN * 64];   // 32 KB

    const uint32_t bid  = blockIdx.x;
    const uint32_t sk   = bid & 31u;
    const uint32_t mblk = bid >> 5;

    const uint32_t tid  = threadIdx.x;
    const uint32_t lane = tid & 63u;
    const uint32_t wave = tid >> 6;          // [0,8)

    // ---- A staging: one row-pair per thread, fp32 -> bf16, swizzled write
    const uint32_t ac   = tid & 7u;          // k-chunk (8 floats)
    const uint32_t arow = tid >> 3;          // [0,64): rows arow, arow+64
    const uint32_t aswz = (ac ^ (arow & 7u)) * 8u;   // same for row+64
    const float* xg = x + (size_t)(mblk * BM + arow) * K_DIM + sk * KC + ac * 8u;

    // ---- B staging: async identity copy of pre-swizzled tiles
    const uint16_t* wg_base = Wsw + (size_t)(sk * NKI) * 16384u;

    // ---- fragment addressing
    const uint32_t mloc = lane & 15u;
    const uint32_t quad = lane >> 4;
    const uint32_t wm = wave >> 2, wn = wave & 3u;
    const uint32_t sw0 = ((quad) ^ (mloc & 7u)) * 8u;        // ks=0
    const uint32_t sw1 = ((4u + quad) ^ (mloc & 7u)) * 8u;   // ks=1
    const uint32_t aRow0 = (wm * 64u + mloc) * 64u;
    const uint32_t bRow0 = (wn * 64u + mloc) * 64u;

    f32x4 acc[4][4];
#pragma unroll
    for (int i = 0; i < 4; ++i)
#pragma unroll
        for (int j = 0; j < 4; ++j) acc[i][j] = (f32x4){0.f, 0.f, 0.f, 0.f};

    for (uint32_t it = 0; it < NKI; ++it) {
        // B: 2048 chunks of 16B; 4 async_load16 per thread (wave-uniform base)
        const uint16_t* wg_tile = wg_base + (size_t)it * 16384u;
#pragma unroll
        for (int j = 0; j < 4; ++j) {
            uint32_t instr = wave * 4u + (uint32_t)j;      // [0,32)
            const uint16_t* g = wg_tile + (size_t)(instr * 64u + lane) * 8u;
            async_load16((const void*)g, (void*)&Bs[instr * 512u]);
        }
        // A: rows arow, arow+64; 8 floats each; convert + swizzled write
#pragma unroll
        for (int j = 0; j < 2; ++j) {
            const float* g = xg + (size_t)(j * 64) * K_DIM + it * BK;
            f32x4 v0 = *(const f32x4*)(g);
            f32x4 v1 = *(const f32x4*)(g + 4);
            uint32_t q0 = pack2_bf16(v0[0], v0[1]);
            uint32_t q1 = pack2_bf16(v0[2], v0[3]);
            uint32_t q2 = pack2_bf16(v1[0], v1[1]);
            uint32_t q3 = pack2_bf16(v1[2], v1[3]);
            *(uint4*)(&As[(arow + (uint32_t)j * 64u) * 64u + aswz]) =
                make_uint4(q0, q1, q2, q3);
        }
        __syncthreads();

#pragma unroll
        for (int ks = 0; ks < 2; ++ks) {
            const uint32_t sw = ks ? sw1 : sw0;
            s16x8 af[4];
#pragma unroll
            for (int t = 0; t < 4; ++t)
                af[t] = *(const s16x8*)(&As[aRow0 + (uint32_t)t * 1024u + sw]);
#pragma unroll
            for (int nt = 0; nt < 4; ++nt) {
                s16x8 bf = *(const s16x8*)(&Bs[bRow0 + (uint32_t)nt * 1024u + sw]);
#pragma unroll
                for (int mt = 0; mt < 4; ++mt)
                    acc[mt][nt] = __builtin_amdgcn_mfma_f32_16x16x32_bf16(
                        af[mt], bf, acc[mt][nt], 0, 0, 0);
            }
        }
        __syncthreads();
    }

    // epilogue: plain stores of the split-K partial
    float* po_base = part + (size_t)sk * OUT_ELEMS;
    const uint32_t orow0 = mblk * BM + wm * 64u + quad * 4u;
    const uint32_t ocol0 = wn * 64u + mloc;
#pragma unroll
    for (int mt = 0; mt < 4; ++mt) {
#pragma unroll
        for (int nt = 0; nt < 4; ++nt) {
            float* po = po_base + (size_t)(orow0 + (uint32_t)mt * 16u) * R_DIM +
                        ocol0 + (uint32_t)nt * 16u;
#pragma unroll
            for (int i = 0; i < 4; ++i)
                po[(size_t)i * R_DIM] = acc[mt][nt][i];
        }
    }
}

// ---------------------------------------------------------------------------
// Kernel 3: out[i] = sum_sk part[sk][i], float4 per thread.
// ---------------------------------------------------------------------------
__global__ __launch_bounds__(256) void reduce_kernel(
        const float* __restrict__ part, float* __restrict__ out) {
    uint32_t i = (blockIdx.x * 256u + threadIdx.x) * 4u;
    f32x4 s = (f32x4){0.f, 0.f, 0.f, 0.f};
#pragma unroll
    for (uint32_t skk = 0; skk < SK; ++skk)
        s += *(const f32x4*)(part + (size_t)skk * OUT_ELEMS + i);
    *(f32x4*)(out + i) = s;
}

extern "C" void kernel_launch(void* const* d_in, const int* in_sizes, int n_in,
                              void* d_out, int out_size, void* d_ws, size_t ws_size,
                              hipStream_t stream) {
    const float* x  = (const float*)d_in[0];
    const float* U0 = (const float*)d_in[1];
    const float* U1 = (const float*)d_in[2];
    const float* U2 = (const float*)d_in[3];
    float* out = (float*)d_out;

    uint16_t* Wsw = (uint16_t*)d_ws;                          // 16 MiB
    float* part = (float*)((char*)d_ws + (32u << 20));        // 64 MiB partials

    wgen_kernel<<<512, 256, 0, stream>>>(U0, U1, U2, Wsw);
    gemm_kernel<<<512, 512, 0, stream>>>(x, Wsw, part);
    reduce_kernel<<<OUT_ELEMS / 4 / 256, 256, 0, stream>>>(part, out);
}